// Round 3
// baseline (357.458 us; speedup 1.0000x reference)
//
#include <hip/hip_runtime.h>
#include <hip/hip_fp16.h>

// FrameConsistencyLoss: mean over (N,64) of (proj_a - proj_b)^2,
// proj_x[i] = x[i] @ W[ids_x[i]] + b[ids_x[i]]; N=2e6, REL_DIM=14, CAN_DIM=64, 4 experts.
//
// R3: embedded-diff MFMA with quad-aligned k-permutation, no LDS in the loop.
//   emb(x,e)[k]: x at pairs q=7e..7e+6, one-hot +1 at k=56+e (bias rows of W~).
//   e-fragment = emb(a,ea) - emb(b,eb) built directly in f16 registers:
//   k-mapping chosen as pair q(quad,sd) = 7*quad + sd (sd=0..6), q=28+quad for slot 7,
//   applied to BOTH A and W~ fragments (k-permutation cancels in MFMA), so the
//   per-lane expert window select is: yd[sd] = (ea==quad ? ra[sd]:0) - (eb==quad ? rb[sd]:0).
//   D = e_frag @ W~ accumulated over K=64 via 2 chained mfma_f32_16x16x32_f16 per col-tile;
//   loss += sum(D^2) -- layout-permutation-invariant (R1 verified this numerics family).
// W~ fragment image built once per block into 8KB LDS, waves load via ds_read_b128.

#define N_ROWS  2000000
#define N_TILES (N_ROWS / 16)    // 125000
#define N_PAIRS (N_TILES / 2)    // 62500
#define NBLK    3125             // 12500 waves -> exactly 5 pairs/wave
#define NTHR    256

typedef _Float16     h2 __attribute__((ext_vector_type(2)));
typedef _Float16     h8 __attribute__((ext_vector_type(8)));
typedef float        f4 __attribute__((ext_vector_type(4)));
typedef unsigned int u4 __attribute__((ext_vector_type(4)));

__device__ __forceinline__ unsigned int pkrtz(float a, float b) {
    return __builtin_bit_cast(unsigned int, __builtin_amdgcn_cvt_pkrtz(a, b));
}
__device__ __forceinline__ unsigned int hsub2(unsigned int a, unsigned int b) {
    h2 r = __builtin_bit_cast(h2, a) - __builtin_bit_cast(h2, b);
    return __builtin_bit_cast(unsigned int, r);
}
__device__ __forceinline__ float ldW(const float* W, const float* BIAS, int k, int c) {
    if (k < 56) return W[k * 64 + c];          // (4,14,64) row-major: k = e*14+kk
    if (k < 60) return BIAS[(k - 56) * 64 + c];
    return 0.0f;
}

__global__ void __launch_bounds__(NTHR)
frame_loss(const float* __restrict__ A, const float* __restrict__ B,
           const int* __restrict__ IDA, const int* __restrict__ IDB,
           const float* __restrict__ W, const float* __restrict__ BIAS,
           float* __restrict__ out)
{
    __shared__ alignas(16) unsigned int sW[2048];   // 8 frags x 64 lanes x 4 dwords

    const int tid = threadIdx.x;

    // ---- Build W~ B-fragment image in LDS (once per block, RTE rounding) ----
    // fragment f = ct*2+s; lane l=(sub,quad); dword d; k = 14*quad+2*sd (sd<7) else 56+2*quad.
#pragma unroll
    for (int it = 0; it < 8; ++it) {
        const int idx = tid + it * 256;       // == f*256 + l*4 + d
        const int f = idx >> 8, l = (idx >> 2) & 63, d = idx & 3;
        const int lsub = l & 15, lquad = l >> 4, ct = f >> 1, s = f & 1;
        const int c = ct * 16 + lsub, sd = s * 4 + d;
        const int k = (sd < 7) ? (14 * lquad + 2 * sd) : (56 + 2 * lquad);
        h2 p;
        p.x = (_Float16)ldW(W, BIAS, k, c);
        p.y = (_Float16)ldW(W, BIAS, k + 1, c);
        sW[idx] = __builtin_bit_cast(unsigned int, p);
    }
    __syncthreads();

    const int lane = tid & 63;
    const int sub  = lane & 15;
    const int quad = lane >> 4;

    u4 wf[8];
#pragma unroll
    for (int f = 0; f < 8; ++f)
        wf[f] = *(const u4*)&sW[f * 256 + lane * 4];   // ds_read_b128

    const int wave   = blockIdx.x * (NTHR / 64) + (tid >> 6);
    const int nwaves = NBLK * (NTHR / 64);

    float ls0 = 0.0f, ls1 = 0.0f;

    for (int pr = wave; pr < N_PAIRS; pr += nwaves) {
        const int base0 = pr * 32;   // two 16-row tiles

        unsigned int pa[2][7], pb[2][7];
        int ia[2], ib[2];

        // ---- hoisted loads + convert for both tiles (MLP) ----
#pragma unroll
        for (int u = 0; u < 2; ++u) {
            const int row = base0 + u * 16 + sub;
            const float* ra = A + (size_t)row * 14;
            const float* rb = B + (size_t)row * 14;
            float4 xa0 = *(const float4*)(ra);        // dword-aligned x4 loads: OK on gfx950
            float4 xa1 = *(const float4*)(ra + 4);
            float4 xa2 = *(const float4*)(ra + 8);
            float2 xa3 = *(const float2*)(ra + 12);
            float4 xb0 = *(const float4*)(rb);
            float4 xb1 = *(const float4*)(rb + 4);
            float4 xb2 = *(const float4*)(rb + 8);
            float2 xb3 = *(const float2*)(rb + 12);
            ia[u] = IDA[row];
            ib[u] = IDB[row];
            pa[u][0] = pkrtz(xa0.x, xa0.y); pa[u][1] = pkrtz(xa0.z, xa0.w);
            pa[u][2] = pkrtz(xa1.x, xa1.y); pa[u][3] = pkrtz(xa1.z, xa1.w);
            pa[u][4] = pkrtz(xa2.x, xa2.y); pa[u][5] = pkrtz(xa2.z, xa2.w);
            pa[u][6] = pkrtz(xa3.x, xa3.y);
            pb[u][0] = pkrtz(xb0.x, xb0.y); pb[u][1] = pkrtz(xb0.z, xb0.w);
            pb[u][2] = pkrtz(xb1.x, xb1.y); pb[u][3] = pkrtz(xb1.z, xb1.w);
            pb[u][4] = pkrtz(xb2.x, xb2.y); pb[u][5] = pkrtz(xb2.z, xb2.w);
            pb[u][6] = pkrtz(xb3.x, xb3.y);
        }

        // ---- per-tile: build e-fragment, 8 MFMAs, square-accumulate ----
#pragma unroll
        for (int u = 0; u < 2; ++u) {
            const bool ma = (ia[u] == quad);
            const bool mb = (ib[u] == quad);
            unsigned int yd[8];
#pragma unroll
            for (int sd = 0; sd < 7; ++sd) {
                const unsigned int va = ma ? pa[u][sd] : 0u;
                const unsigned int vb = mb ? pb[u][sd] : 0u;
                yd[sd] = hsub2(va, vb);
            }
            // one-hot slot (pair q = 28+quad -> k = 56+2quad,57+2quad = bias rows)
            const unsigned int ta = 0x3C00u << ((ia[u] & 1) << 4);
            const unsigned int tb = 0x3C00u << ((ib[u] & 1) << 4);
            const unsigned int va7 = (quad == (ia[u] >> 1)) ? ta : 0u;
            const unsigned int vb7 = (quad == (ib[u] >> 1)) ? tb : 0u;
            yd[7] = hsub2(va7, vb7);

            u4 lo4; lo4.x = yd[0]; lo4.y = yd[1]; lo4.z = yd[2]; lo4.w = yd[3];
            u4 hi4; hi4.x = yd[4]; hi4.y = yd[5]; hi4.z = yd[6]; hi4.w = yd[7];
            const h8 e0 = __builtin_bit_cast(h8, lo4);
            const h8 e1 = __builtin_bit_cast(h8, hi4);

#pragma unroll
            for (int ct = 0; ct < 4; ++ct) {
                const f4 z = {0.0f, 0.0f, 0.0f, 0.0f};
                f4 acc;
                acc = __builtin_amdgcn_mfma_f32_16x16x32_f16(
                          e0, __builtin_bit_cast(h8, wf[ct * 2 + 0]), z, 0, 0, 0);
                acc = __builtin_amdgcn_mfma_f32_16x16x32_f16(
                          e1, __builtin_bit_cast(h8, wf[ct * 2 + 1]), acc, 0, 0, 0);
                ls0 = fmaf(acc[0], acc[0], ls0);
                ls1 = fmaf(acc[1], acc[1], ls1);
                ls0 = fmaf(acc[2], acc[2], ls0);
                ls1 = fmaf(acc[3], acc[3], ls1);
            }
        }
    }

    float lsum = ls0 + ls1;
#pragma unroll
    for (int off = 32; off > 0; off >>= 1)
        lsum += __shfl_down(lsum, off, 64);
    if (lane == 0)
        atomicAdd(out, lsum * (1.0f / 128000000.0f));   // 1/(N*64)
}

extern "C" void kernel_launch(void* const* d_in, const int* in_sizes, int n_in,
                              void* d_out, int out_size, void* d_ws, size_t ws_size,
                              hipStream_t stream) {
    const float* A    = (const float*)d_in[0];
    const float* B    = (const float*)d_in[1];
    const int*   IDA  = (const int*)d_in[2];
    const int*   IDB  = (const int*)d_in[3];
    const float* W    = (const float*)d_in[4];
    const float* BIAS = (const float*)d_in[5];
    float* out = (float*)d_out;

    hipMemsetAsync(out, 0, sizeof(float), stream);
    frame_loss<<<dim3(NBLK), dim3(NTHR), 0, stream>>>(A, B, IDA, IDB, W, BIAS, out);
}

// Round 4
// 272.733 us; speedup vs baseline: 1.3107x; 1.3107x over previous
//
#include <hip/hip_runtime.h>
#include <hip/hip_fp16.h>

// FrameConsistencyLoss: mean over (N,64) of (proj_a - proj_b)^2,
// proj_x[i] = x[i] @ W[ids_x[i]] + b[ids_x[i]]; N=2e6, REL_DIM=14, CAN_DIM=64, 4 experts.
//
// R4: embedded-DIFF MFMA (one matrix, not two), double-buffered LDS, single-wave
// blocks (64 thr) => NO barriers anywhere in the loop; persistent grid of 2048
// blocks (8/CU); per-block partial -> d_ws, tiny stage-2 reduction kernel.
//   Row r: diff_emb[k]: window 14*ea..+13 gets +a (f16), window 14*eb..+13 gets -b,
//   one-hot +1 at k=56+ea, -1 at k=56+eb (bias rows of W~); if ea==eb the windows
//   merge to (a-b) and the one-hots cancel. D = diff_emb @ W~ via 2 chained
//   mfma_f32_16x16x32_f16 per (row-tile, col-tile); loss += sum(D^2) --
//   invariant to fragment layout permutations (A/B k-mappings are symmetric).

#define N_ROWS   2000000
#define N_CHUNKS (N_ROWS / 64)   // 31250 chunks of 64 rows
#define NBLK     2048            // 8 blocks/CU x 256 CUs, persistent
#define LDSW     36              // dwords per LDS row (64 ushorts data + 8 pad)

typedef _Float16     h8 __attribute__((ext_vector_type(8)));
typedef float        f4 __attribute__((ext_vector_type(4)));
typedef unsigned int u4 __attribute__((ext_vector_type(4)));

__device__ __forceinline__ unsigned int pkrtz(float a, float b) {
    return __builtin_bit_cast(unsigned int, __builtin_amdgcn_cvt_pkrtz(a, b));
}

struct RowRegs {
    float a[14], b[14];
    int ea, eb;
};

__device__ __forceinline__ RowRegs load_chunk(int c, int lane,
        const float* __restrict__ A, const float* __restrict__ B,
        const int* __restrict__ IDA, const int* __restrict__ IDB) {
    RowRegs r;
    const int row = c * 64 + lane;
    const float* ra = A + (size_t)row * 14;
    const float* rb = B + (size_t)row * 14;
    float4 a0 = *(const float4*)(ra + 0);
    float4 a1 = *(const float4*)(ra + 4);
    float4 a2 = *(const float4*)(ra + 8);
    float2 a3 = *(const float2*)(ra + 12);
    float4 b0 = *(const float4*)(rb + 0);
    float4 b1 = *(const float4*)(rb + 4);
    float4 b2 = *(const float4*)(rb + 8);
    float2 b3 = *(const float2*)(rb + 12);
    r.ea = IDA[row];
    r.eb = IDB[row];
    r.a[0]=a0.x; r.a[1]=a0.y; r.a[2]=a0.z; r.a[3]=a0.w;
    r.a[4]=a1.x; r.a[5]=a1.y; r.a[6]=a1.z; r.a[7]=a1.w;
    r.a[8]=a2.x; r.a[9]=a2.y; r.a[10]=a2.z; r.a[11]=a2.w;
    r.a[12]=a3.x; r.a[13]=a3.y;
    r.b[0]=b0.x; r.b[1]=b0.y; r.b[2]=b0.z; r.b[3]=b0.w;
    r.b[4]=b1.x; r.b[5]=b1.y; r.b[6]=b1.z; r.b[7]=b1.w;
    r.b[8]=b2.x; r.b[9]=b2.y; r.b[10]=b2.z; r.b[11]=b2.w;
    r.b[12]=b3.x; r.b[13]=b3.y;
    return r;
}

__device__ __forceinline__ void scatter_chunk(unsigned int* __restrict__ row32,
                                              const RowRegs& r) {
    const u4 z = {0u, 0u, 0u, 0u};
#pragma unroll
    for (int t = 0; t < 8; ++t) ((u4*)row32)[t] = z;   // zero dwords 0..31 (k=0..63)
    if (r.ea == r.eb) {
#pragma unroll
        for (int t = 0; t < 7; ++t)
            row32[7 * r.ea + t] = pkrtz(r.a[2*t] - r.b[2*t], r.a[2*t+1] - r.b[2*t+1]);
        // one-hots cancel: dwords 28..29 stay zero
    } else {
#pragma unroll
        for (int t = 0; t < 7; ++t)
            row32[7 * r.ea + t] = pkrtz(r.a[2*t], r.a[2*t+1]);
#pragma unroll
        for (int t = 0; t < 7; ++t)
            row32[7 * r.eb + t] = pkrtz(-r.b[2*t], -r.b[2*t+1]);
        const unsigned wa = 0x3C00u << ((r.ea & 1) * 16);   // +1.0h at k=56+ea
        const unsigned wb = 0xBC00u << ((r.eb & 1) * 16);   // -1.0h at k=56+eb
        const int ja = 28 + (r.ea >> 1), jb = 28 + (r.eb >> 1);
        if (ja == jb) row32[ja] = wa | wb;
        else { row32[ja] = wa; row32[jb] = wb; }
    }
}

__device__ __forceinline__ void compute_chunk(const unsigned int* __restrict__ sbuf,
                                              int sub, int quad, const h8* wf,
                                              float* ls) {
#pragma unroll
    for (int t = 0; t < 4; ++t) {
        const unsigned int* fr = sbuf + (t * 16 + sub) * LDSW + quad * 4;
        u4 lo = *(const u4*)fr;          // k = quad*8 .. +7
        u4 hi = *(const u4*)(fr + 16);   // k = 32+quad*8 .. +7
        const h8 e0 = __builtin_bit_cast(h8, lo);
        const h8 e1 = __builtin_bit_cast(h8, hi);
#pragma unroll
        for (int ct = 0; ct < 4; ++ct) {
            const f4 z = {0.0f, 0.0f, 0.0f, 0.0f};
            f4 acc = __builtin_amdgcn_mfma_f32_16x16x32_f16(e0, wf[ct * 2 + 0], z, 0, 0, 0);
            acc     = __builtin_amdgcn_mfma_f32_16x16x32_f16(e1, wf[ct * 2 + 1], acc, 0, 0, 0);
#pragma unroll
            for (int rr = 0; rr < 4; ++rr)
                ls[rr] = fmaf(acc[rr], acc[rr], ls[rr]);
        }
    }
}

__global__ void __launch_bounds__(64, 2)
frame_loss(const float* __restrict__ A, const float* __restrict__ B,
           const int* __restrict__ IDA, const int* __restrict__ IDB,
           const float* __restrict__ W, const float* __restrict__ BIAS,
           float* __restrict__ ws)
{
    __shared__ alignas(16) unsigned int s0[64 * LDSW];  // 9216 B
    __shared__ alignas(16) unsigned int s1[64 * LDSW];  // 9216 B

    const int lane = threadIdx.x;        // block = 1 wave
    const int sub  = lane & 15;
    const int quad = lane >> 4;

    // ---- W~ B-fragments in registers (once): frag f=ct*2+s, elem j:
    // k = s*32 + quad*8 + j, col c = ct*16 + sub. W~[k][c] = W (k<56), bias (56..59), 0.
    h8 wf[8];
#pragma unroll
    for (int ct = 0; ct < 4; ++ct)
#pragma unroll
        for (int s = 0; s < 2; ++s) {
            h8 f;
            const int c = ct * 16 + sub;
#pragma unroll
            for (int j = 0; j < 8; ++j) {
                const int k = s * 32 + quad * 8 + j;
                float v = 0.0f;
                if (k < 56)       v = W[k * 64 + c];           // (4,14,64) flat == W~ rows 0..55
                else if (k < 60)  v = BIAS[(k - 56) * 64 + c]; // bias rows 56..59
                f[j] = (_Float16)v;
            }
            wf[ct * 2 + s] = f;
        }

    float ls[4] = {0.0f, 0.0f, 0.0f, 0.0f};
    unsigned int* const myrow0 = s0 + lane * LDSW;
    unsigned int* const myrow1 = s1 + lane * LDSW;

    int c = blockIdx.x;
    RowRegs rr = load_chunk(c, lane, A, B, IDA, IDB);
    scatter_chunk(myrow0, rr);

    while (true) {
        int n = c + NBLK;
        bool more = (n < N_CHUNKS);
        if (more) rr = load_chunk(n, lane, A, B, IDA, IDB);   // overlap with compute below
        compute_chunk(s0, sub, quad, wf, ls);
        if (!more) break;
        scatter_chunk(myrow1, rr);
        c = n;

        n = c + NBLK;
        more = (n < N_CHUNKS);
        if (more) rr = load_chunk(n, lane, A, B, IDA, IDB);
        compute_chunk(s1, sub, quad, wf, ls);
        if (!more) break;
        scatter_chunk(myrow0, rr);
        c = n;
    }

    float lsum = ls[0] + ls[1] + ls[2] + ls[3];
#pragma unroll
    for (int off = 32; off > 0; off >>= 1)
        lsum += __shfl_down(lsum, off, 64);
    if (lane == 0)
        ws[blockIdx.x] = lsum;     // no atomic: per-block partial
}

__global__ void __launch_bounds__(256)
reduce_partials(const float* __restrict__ ws, float* __restrict__ out)
{
    const int tid = threadIdx.x;
    float s = 0.0f;
#pragma unroll
    for (int i = tid; i < NBLK; i += 256) s += ws[i];
#pragma unroll
    for (int off = 32; off > 0; off >>= 1)
        s += __shfl_down(s, off, 64);
    __shared__ float tmp[4];
    if ((tid & 63) == 0) tmp[tid >> 6] = s;
    __syncthreads();
    if (tid == 0)
        out[0] = (tmp[0] + tmp[1] + tmp[2] + tmp[3]) * (1.0f / 128000000.0f); // 1/(N*64)
}

extern "C" void kernel_launch(void* const* d_in, const int* in_sizes, int n_in,
                              void* d_out, int out_size, void* d_ws, size_t ws_size,
                              hipStream_t stream) {
    const float* A    = (const float*)d_in[0];
    const float* B    = (const float*)d_in[1];
    const int*   IDA  = (const int*)d_in[2];
    const int*   IDB  = (const int*)d_in[3];
    const float* W    = (const float*)d_in[4];
    const float* BIAS = (const float*)d_in[5];
    float* ws  = (float*)d_ws;     // needs NBLK*4 = 8 KB of scratch
    float* out = (float*)d_out;

    frame_loss<<<dim3(NBLK), dim3(64), 0, stream>>>(A, B, IDA, IDB, W, BIAS, ws);
    reduce_partials<<<dim3(1), dim3(256), 0, stream>>>(ws, out);
}